// Round 10
// baseline (143.576 us; speedup 1.0000x reference)
//
#include <hip/hip_runtime.h>
#include <hip/hip_bf16.h>

#define EPS 1e-6f
#define LN2 0.6931471805599453f

typedef float f4 __attribute__((ext_vector_type(4)));

constexpr int B = 64;
constexpr int NPB = 512 * 512;                     // elements per batch = 262144
constexpr int BLOCKS_PER_BATCH = 32;
constexpr int NBLK = B * BLOCKS_PER_BATCH;         // 2048 blocks
constexpr int THREADS = 256;                       // 4 waves
constexpr int CHUNK = 8192;                        // elements per block per array
constexpr int F4_PER_THREAD = CHUNK / 4 / THREADS; // 8

__device__ __forceinline__ float waveReduce(float v) {
    #pragma unroll
    for (int off = 32; off > 0; off >>= 1) v += __shfl_down(v, off, 64);
    return v;
}

__device__ __forceinline__ void stage16(const float* g, float* l) {
    __builtin_amdgcn_global_load_lds(
        (const __attribute__((address_space(1))) void*)g,
        (__attribute__((address_space(3))) void*)l, 16, 0, 0);
}

// Dual-path read kernel: pred streams through the LDS-DMA queue while true
// streams through the VMEM-return queue (nt loads). S = sum t*log2 t (phase A,
// under the DMA) minus sum t*log2 p (phase B, from LDS).
__global__ __launch_bounds__(THREADS) void kl_partial(
        const float* __restrict__ pred, const float* __restrict__ truem,
        float* __restrict__ ws) {
    __shared__ float lds_p[CHUNK];                 // 32 KB

    const size_t base = (size_t)blockIdx.x * CHUNK;
    const int wave = threadIdx.x >> 6;
    const int lane = threadIdx.x & 63;

    // Issue all pred staging: each wave DMAs its 8 KB slice (8 x 1 KB ops).
    #pragma unroll
    for (int j = 0; j < 8; ++j) {
        const int off = wave * 2048 + j * 256;     // floats
        stage16(pred + base + off + lane * 4, lds_p + off);
    }

    // Phase A (DMA in flight): true via VMEM nt loads; St and sum t*log2 t.
    const f4* t4 = (const f4*)(truem + base);
    f4 t[F4_PER_THREAD];
    float st = 0.f, s_tt = 0.f;
    #pragma unroll
    for (int j = 0; j < F4_PER_THREAD; ++j) {
        t[j] = __builtin_nontemporal_load(&t4[threadIdx.x + j * THREADS]);
        st += (t[j].x + t[j].y) + (t[j].z + t[j].w);
        float tx = t[j].x + EPS, ty = t[j].y + EPS;
        float tz = t[j].z + EPS, tw = t[j].w + EPS;
        s_tt += tx * __log2f(tx);
        s_tt += ty * __log2f(ty);
        s_tt += tz * __log2f(tz);
        s_tt += tw * __log2f(tw);
    }

    __syncthreads();   // vmcnt(0) drain + barrier: pred now in LDS

    // Phase B: pred from LDS; Sp and sum t*log2 p (t still in registers).
    const f4* lp = (const f4*)lds_p;
    float sp = 0.f, s_tp = 0.f;
    #pragma unroll
    for (int j = 0; j < F4_PER_THREAD; ++j) {
        f4 p = lp[threadIdx.x + j * THREADS];
        sp += (p.x + p.y) + (p.z + p.w);
        float px = p.x + EPS, py = p.y + EPS, pz = p.z + EPS, pw = p.w + EPS;
        s_tp += (t[j].x + EPS) * __log2f(px);
        s_tp += (t[j].y + EPS) * __log2f(py);
        s_tp += (t[j].z + EPS) * __log2f(pz);
        s_tp += (t[j].w + EPS) * __log2f(pw);
    }

    float s = s_tt - s_tp;
    sp = waveReduce(sp);
    st = waveReduce(st);
    s  = waveReduce(s);

    __shared__ float red[3][THREADS / 64];
    if (lane == 0) { red[0][wave] = sp; red[1][wave] = st; red[2][wave] = s; }
    __syncthreads();
    if (threadIdx.x == 0) {
        float a0 = 0.f, a1 = 0.f, a2 = 0.f;
        #pragma unroll
        for (int w = 0; w < THREADS / 64; ++w) {
            a0 += red[0][w]; a1 += red[1][w]; a2 += red[2][w];
        }
        ws[blockIdx.x]            = a0;   // Sp partial (without eps)
        ws[NBLK + blockIdx.x]     = a1;   // St partial (without eps)
        ws[2 * NBLK + blockIdx.x] = a2;   // S partial, log2 units
    }
}

// Kernel 2: sum 32 partials per batch, fold eps + ln2, mean over B.
__global__ __launch_bounds__(64) void kl_final(
        const float* __restrict__ ws, float* __restrict__ out) {
    const int b = threadIdx.x;   // one wave, one batch per lane
    float Sp = 0.f, St = 0.f, S = 0.f;
    #pragma unroll
    for (int k = 0; k < BLOCKS_PER_BATCH; ++k) {
        const int idx = b * BLOCKS_PER_BATCH + k;
        Sp += ws[idx];
        St += ws[NBLK + idx];
        S  += ws[2 * NBLK + idx];
    }
    const float epsN = (float)NPB * EPS;   // sum of the per-element +EPS
    Sp += epsN;
    St += epsN;
    float kl = (S * LN2) / St + logf(Sp / St);
    kl = waveReduce(kl);
    if (b == 0) out[0] = kl * (1.0f / B);
}

extern "C" void kernel_launch(void* const* d_in, const int* in_sizes, int n_in,
                              void* d_out, int out_size, void* d_ws, size_t ws_size,
                              hipStream_t stream) {
    const float* pred  = (const float*)d_in[0];
    const float* truem = (const float*)d_in[1];
    float* out = (float*)d_out;
    float* ws  = (float*)d_ws;

    kl_partial<<<NBLK, THREADS, 0, stream>>>(pred, truem, ws);
    kl_final<<<1, 64, 0, stream>>>(ws, out);
}

// Round 11
// 136.861 us; speedup vs baseline: 1.0491x; 1.0491x over previous
//
#include <hip/hip_runtime.h>
#include <hip/hip_bf16.h>

#define EPS 1e-6f
#define LN2 0.6931471805599453f

typedef float f4 __attribute__((ext_vector_type(4)));

constexpr int B = 64;
constexpr int NPB = 512 * 512;                     // elements per batch = 262144
constexpr int BLOCKS_PER_BATCH = 16;
constexpr int NBLK = B * BLOCKS_PER_BATCH;         // 1024 blocks = 4/CU
constexpr int THREADS = 256;
constexpr int CHUNK = NPB / BLOCKS_PER_BATCH;      // 16384 elements per block
constexpr int ITERS = CHUNK / 4 / THREADS;         // 16 float4-pairs per thread

__device__ __forceinline__ float waveReduce(float v) {
    #pragma unroll
    for (int off = 32; off > 0; off >>= 1) v += __shfl_down(v, off, 64);
    return v;
}

// Best variant (R9): nt loads (bypass dirty-L3 retention) + depth-2 rotating
// register pipeline. Seven structures pin the same ~3.1-3.6 TB/s read-service
// ceiling; this one is the fastest and simplest.
__global__ __launch_bounds__(THREADS) void kl_partial(
        const float* __restrict__ pred, const float* __restrict__ truem,
        float* __restrict__ ws) {
    const size_t base = (size_t)blockIdx.x * CHUNK;
    const f4* p4 = (const f4*)(pred + base);
    const f4* t4 = (const f4*)(truem + base);

    float sp = 0.f, st = 0.f, s = 0.f;

    f4 pc = __builtin_nontemporal_load(&p4[threadIdx.x]);
    f4 tc = __builtin_nontemporal_load(&t4[threadIdx.x]);
    #pragma unroll
    for (int j = 1; j <= ITERS; ++j) {
        f4 pn, tn;
        if (j < ITERS) {
            pn = __builtin_nontemporal_load(&p4[threadIdx.x + j * THREADS]);
            tn = __builtin_nontemporal_load(&t4[threadIdx.x + j * THREADS]);
        }
        // consume cur while next is in flight
        sp += (pc.x + pc.y) + (pc.z + pc.w);
        st += (tc.x + tc.y) + (tc.z + tc.w);
        float px = pc.x + EPS, py = pc.y + EPS, pz = pc.z + EPS, pw = pc.w + EPS;
        float tx = tc.x + EPS, ty = tc.y + EPS, tz = tc.z + EPS, tw = tc.w + EPS;
        s += tx * (__log2f(tx) - __log2f(px));
        s += ty * (__log2f(ty) - __log2f(py));
        s += tz * (__log2f(tz) - __log2f(pz));
        s += tw * (__log2f(tw) - __log2f(pw));
        pc = pn; tc = tn;
    }

    sp = waveReduce(sp);
    st = waveReduce(st);
    s  = waveReduce(s);

    __shared__ float red[3][THREADS / 64];
    const int wave = threadIdx.x >> 6;
    const int lane = threadIdx.x & 63;
    if (lane == 0) { red[0][wave] = sp; red[1][wave] = st; red[2][wave] = s; }
    __syncthreads();
    if (threadIdx.x == 0) {
        float a0 = 0.f, a1 = 0.f, a2 = 0.f;
        #pragma unroll
        for (int w = 0; w < THREADS / 64; ++w) {
            a0 += red[0][w]; a1 += red[1][w]; a2 += red[2][w];
        }
        ws[blockIdx.x]            = a0;   // Sp partial (without eps)
        ws[NBLK + blockIdx.x]     = a1;   // St partial (without eps)
        ws[2 * NBLK + blockIdx.x] = a2;   // S partial, log2 units
    }
}

// Kernel 2: sum 16 partials per batch, fold eps + ln2, mean over B.
__global__ __launch_bounds__(64) void kl_final(
        const float* __restrict__ ws, float* __restrict__ out) {
    const int b = threadIdx.x;   // one wave, one batch per lane
    float Sp = 0.f, St = 0.f, S = 0.f;
    #pragma unroll
    for (int k = 0; k < BLOCKS_PER_BATCH; ++k) {
        const int idx = b * BLOCKS_PER_BATCH + k;
        Sp += ws[idx];
        St += ws[NBLK + idx];
        S  += ws[2 * NBLK + idx];
    }
    const float epsN = (float)NPB * EPS;   // sum of the per-element +EPS
    Sp += epsN;
    St += epsN;
    float kl = (S * LN2) / St + logf(Sp / St);
    kl = waveReduce(kl);
    if (b == 0) out[0] = kl * (1.0f / B);
}

extern "C" void kernel_launch(void* const* d_in, const int* in_sizes, int n_in,
                              void* d_out, int out_size, void* d_ws, size_t ws_size,
                              hipStream_t stream) {
    const float* pred  = (const float*)d_in[0];
    const float* truem = (const float*)d_in[1];
    float* out = (float*)d_out;
    float* ws  = (float*)d_ws;

    kl_partial<<<NBLK, THREADS, 0, stream>>>(pred, truem, ws);
    kl_final<<<1, 64, 0, stream>>>(ws, out);
}